// Round 8
// baseline (134.795 us; speedup 1.0000x reference)
//
#include <hip/hip_runtime.h>
#include <math.h>

typedef __bf16 bf16x8 __attribute__((ext_vector_type(8)));
typedef float f32x4 __attribute__((ext_vector_type(4)));

#define MFMA16(a, b, c) __builtin_amdgcn_mfma_f32_16x16x32_bf16(a, b, c, 0, 0, 0)

static constexpr int M_TOT = 8192;   // B*S
static constexpr int DIN = 4096;
static constexpr int DOUT = 4096;
static constexpr int RNK = 64;

__device__ inline unsigned short f2bf(float f) {
    union { float f; unsigned u; } v; v.f = f;
    unsigned r = v.u + 0x7FFFu + ((v.u >> 16) & 1u);   // round-to-nearest-even
    return (unsigned short)(r >> 16);
}

// ---------------------------------------------------------------------------
// Fragment-major layout (unchanged from r7): block (tile,slice) holds the 64
// lanes' bf16x8 contiguously; every wave fragment load = one 1 KB instruction.
// ---------------------------------------------------------------------------
__global__ __launch_bounds__(256) void k_prep(const float* __restrict__ A,
                                              const float* __restrict__ B,
                                              unsigned short* __restrict__ Afrag,
                                              unsigned short* __restrict__ Atfrag,
                                              unsigned short* __restrict__ Bfrag) {
    int i = blockIdx.x * 256 + threadIdx.x;          // 0 .. 262143
    unsigned short ab = f2bf(A[i]);
    int n = i >> 12, k = i & 4095;                   // A[n][k]
    Afrag[(((k >> 5) << 2) + (n >> 4)) * 512 +
          ((((k >> 3) & 3) << 4) + (n & 15)) * 8 + (k & 7)] = ab;
    Atfrag[(((k >> 4) << 1) + (n >> 5)) * 512 +
           ((((n >> 3) & 3) << 4) + (k & 15)) * 8 + (n & 7)] = ab;
    unsigned short bb = f2bf(B[i]);
    int o = i >> 6, r = i & 63;
    Bfrag[(((o >> 4) << 1) + (r >> 5)) * 512 +
          ((((r >> 3) & 3) << 4) + (o & 15)) * 8 + (r & 7)] = bb;
}

// ---------------------------------------------------------------------------
// k1_xa: partial xa = x @ lora_A^T over a 16m x 1024K chunk.
// ONE-SHOT block (kB-shape): 16 front-loaded f32x4/thread (64 KB in flight),
// single stage->barrier->MFMA->reduce, f32 partials out. No loop barriers.
// Grid: 512 m-tiles x 4 K-parts = 2048 blocks, 256 threads.
// ---------------------------------------------------------------------------
__global__ __launch_bounds__(256, 4) void k1_xa(const float* __restrict__ x,
                                                const unsigned short* __restrict__ Afrag,
                                                float* __restrict__ pxa) {
    __shared__ __align__(16) char smem[33024];
    unsigned short (*stage)[1032] = (unsigned short (*)[1032])smem;  // 33 KB
    float (*red)[1024] = (float (*)[1024])smem;                      // 16 KB (aliases)
    int tid = threadIdx.x;
    int wid = tid >> 6, lane = tid & 63;
    int row = lane & 15, kq = lane >> 4;
    int lane8 = lane * 8;
    int mt = blockIdx.x & 511, kpart = blockIdx.x >> 9;
    int m0 = mt * 16;
    int sr = tid >> 4, sc = (tid & 15) * 4;          // 16 threads/row

    // front-load the entire 16x1024 chunk: 16 f32x4 per thread
    const float* xp = x + (size_t)(m0 + sr) * DIN + kpart * 1024 + sc;
    f32x4 r[16];
    #pragma unroll
    for (int p = 0; p < 16; ++p) r[p] = *(const f32x4*)(xp + p * 64);

    #pragma unroll
    for (int p = 0; p < 16; ++p) {
        ushort4 h;
        h.x = f2bf(r[p][0]); h.y = f2bf(r[p][1]); h.z = f2bf(r[p][2]); h.w = f2bf(r[p][3]);
        *(ushort4*)&stage[sr][p * 64 + sc] = h;
    }
    __syncthreads();

    // wave owns K-slice of 256: 8 steps x 4 MFMA
    f32x4 acc0 = {0.f, 0.f, 0.f, 0.f};
    f32x4 acc1 = acc0, acc2 = acc0, acc3 = acc0;
    #pragma unroll
    for (int s = 0; s < 8; ++s) {
        bf16x8 af = *(const bf16x8*)&stage[row][wid * 256 + s * 32 + kq * 8];
        int ks = kpart * 32 + wid * 8 + s;
        const unsigned short* ap = Afrag + (size_t)(ks << 2) * 512 + lane8;
        acc0 = MFMA16(af, *(const bf16x8*)(ap), acc0);
        acc1 = MFMA16(af, *(const bf16x8*)(ap + 512), acc1);
        acc2 = MFMA16(af, *(const bf16x8*)(ap + 1024), acc2);
        acc3 = MFMA16(af, *(const bf16x8*)(ap + 1536), acc3);
    }
    __syncthreads();                                  // stage reads done

    int mb = kq * 4;                                  // C: row=(lane>>4)*4+reg
    #pragma unroll
    for (int rg = 0; rg < 4; ++rg) {
        red[wid][(mb + rg) * 64 + row]      = acc0[rg];
        red[wid][(mb + rg) * 64 + 16 + row] = acc1[rg];
        red[wid][(mb + rg) * 64 + 32 + row] = acc2[rg];
        red[wid][(mb + rg) * 64 + 48 + row] = acc3[rg];
    }
    __syncthreads();
    #pragma unroll
    for (int e = tid; e < 1024; e += 256) {
        float s = red[0][e] + red[1][e] + red[2][e] + red[3][e];
        pxa[(size_t)kpart * M_TOT * RNK + (size_t)(m0 + (e >> 6)) * RNK + (e & 63)] = s;
    }
}

// k1_fin: xa frag-major bf16 <- sum of 4 f32 partials. 512 blocks x 256 thr.
__global__ __launch_bounds__(256) void k1_fin(const float* __restrict__ pxa,
                                              unsigned short* __restrict__ xafrag) {
    int tid = threadIdx.x;
    int mt = blockIdx.x;
    int e0 = tid * 4;
    size_t o = (size_t)(mt * 16 + (e0 >> 6)) * RNK + (e0 & 63);
    f32x4 s0 = *(const f32x4*)(pxa + o);
    f32x4 s1 = *(const f32x4*)(pxa + (size_t)M_TOT * RNK + o);
    f32x4 s2 = *(const f32x4*)(pxa + 2 * (size_t)M_TOT * RNK + o);
    f32x4 s3 = *(const f32x4*)(pxa + 3 * (size_t)M_TOT * RNK + o);
    int ml = e0 >> 6, r0 = e0 & 63;
    ushort4 h;
    h.x = f2bf(s0[0] + s1[0] + s2[0] + s3[0]);
    h.y = f2bf(s0[1] + s1[1] + s2[1] + s3[1]);
    h.z = f2bf(s0[2] + s1[2] + s2[2] + s3[2]);
    h.w = f2bf(s0[3] + s1[3] + s2[3] + s3[3]);
    *(ushort4*)&xafrag[((size_t)(mt * 2 + (r0 >> 5))) * 512 +
                       ((((r0 >> 3) & 3) << 4) + ml) * 8 + (r0 & 7)] = h;
}

// ---------------------------------------------------------------------------
// k2_norm: partial squared row-norms of (bw + 2*B@A) over 16o x 512i chunk.
// Same one-shot shape: 8 front-loaded f32x4/thread, one barrier, no loop.
// Grid: 256 o-tiles x 8 i-parts = 2048 blocks, 256 threads.
// ---------------------------------------------------------------------------
__global__ __launch_bounds__(256, 4) void k2_norm(const float* __restrict__ bw,
                                                  const unsigned short* __restrict__ Bfrag,
                                                  const unsigned short* __restrict__ Atfrag,
                                                  float* __restrict__ pn) {
    __shared__ __align__(16) char smem[33280];
    float (*stagef)[516] = (float (*)[516])smem;     // 33 KB
    float (*part)[16] = (float (*)[16])(smem + 33024);
    int tid = threadIdx.x;
    int wid = tid >> 6, lane = tid & 63;
    int row = lane & 15, kq = lane >> 4;
    int lane8 = lane * 8;
    int ot = blockIdx.x & 255, ipart = blockIdx.x >> 8;
    int o0 = ot * 16;
    int sr = tid >> 4, sc = (tid & 15) * 4;

    // front-load the entire 16x512 chunk: 8 f32x4 per thread
    const float* bwp = bw + (size_t)(o0 + sr) * DIN + ipart * 512 + sc;
    f32x4 q[8];
    #pragma unroll
    for (int p = 0; p < 8; ++p) q[p] = *(const f32x4*)(bwp + p * 64);

    bf16x8 b0 = *(const bf16x8*)(Bfrag + (size_t)(ot * 2) * 512 + lane8);
    bf16x8 b1 = *(const bf16x8*)(Bfrag + (size_t)(ot * 2 + 1) * 512 + lane8);

    #pragma unroll
    for (int p = 0; p < 8; ++p) *(f32x4*)&stagef[sr][p * 64 + sc] = q[p];
    __syncthreads();

    // wave owns i-slice of 128: 8 groups of 16 i
    f32x4 nacc = {0.f, 0.f, 0.f, 0.f};
    #pragma unroll
    for (int g = 0; g < 8; ++g) {
        int iloc = wid * 128 + g * 16;
        int it = (ipart * 512 + iloc) >> 4;
        const unsigned short* atp = Atfrag + (size_t)(it * 2) * 512 + lane8;
        bf16x8 a0 = *(const bf16x8*)(atp);
        bf16x8 a1 = *(const bf16x8*)(atp + 512);
        f32x4 d = {0.f, 0.f, 0.f, 0.f};
        d = MFMA16(a0, b0, d);                       // lane: delta[o=o0+row][i=iloc+kq*4+rg]
        d = MFMA16(a1, b1, d);
        f32x4 wv = *(const f32x4*)&stagef[row][iloc + kq * 4];
        #pragma unroll
        for (int rg = 0; rg < 4; ++rg) {
            float w = wv[rg] + 2.0f * d[rg];
            nacc[rg] += w * w;
        }
    }
    float ns = nacc[0] + nacc[1] + nacc[2] + nacc[3];
    ns += __shfl_xor(ns, 16, 64);
    ns += __shfl_xor(ns, 32, 64);
    if (kq == 0) part[wid][row] = ns;
    __syncthreads();
    if (tid < 16)
        pn[ipart * DOUT + o0 + tid] =
            part[0][tid] + part[1][tid] + part[2][tid] + part[3][tid];
}

// ---------------------------------------------------------------------------
// kB: out = (base + 2 * xa @ lora_B^T) * mag/(sqrt(sum_p pn[p])+eps)
// Two 16m x 256n tiles per block; mscale computed inline from pn partials.
// ---------------------------------------------------------------------------
__global__ __launch_bounds__(256) void kB(const float* __restrict__ base,
                                          const unsigned short* __restrict__ xafrag,
                                          const unsigned short* __restrict__ Bfrag,
                                          const float* __restrict__ pn,
                                          const float* __restrict__ mag,
                                          float* __restrict__ out) {
    __shared__ float dls[32][260];                   // 33.3 KB, +4 pad
    int tid = threadIdx.x;
    int wid = tid >> 6, lane = tid & 63;
    int row = lane & 15, kq = lane >> 4;
    int m0 = blockIdx.x * 32;
    int n0 = blockIdx.y * 256;
    int col = n0 + lane * 4;
    int lane8 = lane * 8;

    // issue epilogue loads early: they retire under the MFMA phase
    f32x4 bpre[2][4];
    #pragma unroll
    for (int h = 0; h < 2; ++h)
        #pragma unroll
        for (int r = 0; r < 4; ++r)
            bpre[h][r] = __builtin_nontemporal_load(
                (const f32x4*)(base + (size_t)(m0 + h * 16 + wid * 4 + r) * DOUT + col));
    f32x4 pnv[8];
    #pragma unroll
    for (int p = 0; p < 8; ++p) pnv[p] = *(const f32x4*)(pn + p * DOUT + col);
    f32x4 mg = *(const f32x4*)(mag + col);

    // MFMA phase: delta = xa @ B^T for two 16x256 tiles
    bf16x8 xb0[2], xb1[2];
    #pragma unroll
    for (int h = 0; h < 2; ++h) {
        size_t mt = (size_t)(blockIdx.x * 2 + h);
        xb0[h] = *(const bf16x8*)(xafrag + (mt * 2) * 512 + lane8);
        xb1[h] = *(const bf16x8*)(xafrag + (mt * 2 + 1) * 512 + lane8);
    }

    #pragma unroll
    for (int nt = 0; nt < 4; ++nt) {
        size_t ntg = (size_t)((n0 + wid * 64 + nt * 16) >> 4);
        bf16x8 a0 = *(const bf16x8*)(Bfrag + (ntg * 2) * 512 + lane8);
        bf16x8 a1 = *(const bf16x8*)(Bfrag + (ntg * 2 + 1) * 512 + lane8);
        #pragma unroll
        for (int h = 0; h < 2; ++h) {
            f32x4 acc = {0.f, 0.f, 0.f, 0.f};
            acc = MFMA16(a0, xb0[h], acc);           // lane: delta[m=row][nloc=kq*4+rg]
            acc = MFMA16(a1, xb1[h], acc);
            *(f32x4*)&dls[h * 16 + row][wid * 64 + nt * 16 + kq * 4] = acc;
        }
    }
    __syncthreads();

    f32x4 msv;
    #pragma unroll
    for (int j = 0; j < 4; ++j) {
        float n2 = 0.f;
        #pragma unroll
        for (int p = 0; p < 8; ++p) n2 += pnv[p][j];
        msv[j] = mg[j] / (sqrtf(n2) + 1e-8f);
    }

    #pragma unroll
    for (int h = 0; h < 2; ++h)
        #pragma unroll
        for (int r = 0; r < 4; ++r) {
            int m = h * 16 + wid * 4 + r;
            f32x4 d = *(const f32x4*)&dls[m][lane * 4];
            size_t gidx = (size_t)(m0 + m) * DOUT + col;
            f32x4 o;
            #pragma unroll
            for (int j = 0; j < 4; ++j) o[j] = (bpre[h][r][j] + 2.0f * d[j]) * msv[j];
            __builtin_nontemporal_store(o, (f32x4*)(out + gidx));
        }
}

extern "C" void kernel_launch(void* const* d_in, const int* in_sizes, int n_in,
                              void* d_out, int out_size, void* d_ws, size_t ws_size,
                              hipStream_t stream) {
    const float* x    = (const float*)d_in[0];   // [2,4096,4096]
    const float* base = (const float*)d_in[1];   // [2,4096,4096]
    const float* bw   = (const float*)d_in[2];   // [4096,4096]
    const float* lA   = (const float*)d_in[3];   // [64,4096]
    const float* lB   = (const float*)d_in[4];   // [4096,64]
    const float* mag  = (const float*)d_in[5];   // [4096]
    float* out = (float*)d_out;

    char* ws = (char*)d_ws;
    unsigned short* Afrag  = (unsigned short*)(ws);                  // 512 KB
    unsigned short* Atfrag = (unsigned short*)(ws + (512u << 10));   // 512 KB
    unsigned short* Bfrag  = (unsigned short*)(ws + (1024u << 10));  // 512 KB
    unsigned short* xafrag = (unsigned short*)(ws + (1536u << 10));  // 1 MB
    float*          pxa    = (float*)(ws + (2560u << 10));           // 8 MB
    float*          pn     = (float*)(ws + (10752u << 10));          // 128 KB

    hipLaunchKernelGGL(k_prep, dim3(1024), dim3(256), 0, stream, lA, lB, Afrag, Atfrag, Bfrag);
    hipLaunchKernelGGL(k1_xa, dim3(2048), dim3(256), 0, stream, x, Afrag, pxa);
    hipLaunchKernelGGL(k2_norm, dim3(2048), dim3(256), 0, stream, bw, Bfrag, Atfrag, pn);
    hipLaunchKernelGGL(k1_fin, dim3(512), dim3(256), 0, stream, pxa, xafrag);
    hipLaunchKernelGGL(kB, dim3(M_TOT / 32, DOUT / 256), dim3(256), 0, stream,
                       base, xafrag, Bfrag, pn, mag, out);
}

// Round 9
// 124.000 us; speedup vs baseline: 1.0871x; 1.0871x over previous
//
#include <hip/hip_runtime.h>
#include <math.h>

typedef __bf16 bf16x8 __attribute__((ext_vector_type(8)));
typedef float f32x4 __attribute__((ext_vector_type(4)));

#define MFMA16(a, b, c) __builtin_amdgcn_mfma_f32_16x16x32_bf16(a, b, c, 0, 0, 0)

static constexpr int M_TOT = 8192;   // B*S
static constexpr int DIN = 4096;
static constexpr int DOUT = 4096;
static constexpr int RNK = 64;

__device__ inline unsigned short f2bf(float f) {
    union { float f; unsigned u; } v; v.f = f;
    unsigned r = v.u + 0x7FFFu + ((v.u >> 16) & 1u);   // round-to-nearest-even
    return (unsigned short)(r >> 16);
}

// ---------------------------------------------------------------------------
// Fragment-major layout: block (tile,slice) holds the 64 lanes' bf16x8
// contiguously; every wave fragment load = one coalesced 1 KB instruction.
// ---------------------------------------------------------------------------
__global__ __launch_bounds__(256) void k_prep(const float* __restrict__ A,
                                              const float* __restrict__ B,
                                              unsigned short* __restrict__ Afrag,
                                              unsigned short* __restrict__ Atfrag,
                                              unsigned short* __restrict__ Bfrag) {
    int i = blockIdx.x * 256 + threadIdx.x;          // 0 .. 262143
    unsigned short ab = f2bf(A[i]);
    int n = i >> 12, k = i & 4095;                   // A[n][k]
    Afrag[(((k >> 5) << 2) + (n >> 4)) * 512 +
          ((((k >> 3) & 3) << 4) + (n & 15)) * 8 + (k & 7)] = ab;
    Atfrag[(((k >> 4) << 1) + (n >> 5)) * 512 +
           ((((n >> 3) & 3) << 4) + (k & 15)) * 8 + (n & 7)] = ab;
    unsigned short bb = f2bf(B[i]);
    int o = i >> 6, r = i & 63;
    Bfrag[(((o >> 4) << 1) + (r >> 5)) * 512 +
          ((((r >> 3) & 3) << 4) + (o & 15)) * 8 + (r & 7)] = bb;
}

// ---------------------------------------------------------------------------
// k1_xa: partial xa = x @ lora_A^T over a 16m x 1024K chunk (one-shot block).
// Grid: 512 m-tiles x 4 K-parts = 2048 blocks, 256 threads.
// ---------------------------------------------------------------------------
__global__ __launch_bounds__(256, 4) void k1_xa(const float* __restrict__ x,
                                                const unsigned short* __restrict__ Afrag,
                                                float* __restrict__ pxa) {
    __shared__ __align__(16) char smem[33024];
    unsigned short (*stage)[1032] = (unsigned short (*)[1032])smem;  // 33 KB
    float (*red)[1024] = (float (*)[1024])smem;                      // 16 KB (aliases)
    int tid = threadIdx.x;
    int wid = tid >> 6, lane = tid & 63;
    int row = lane & 15, kq = lane >> 4;
    int lane8 = lane * 8;
    int mt = blockIdx.x & 511, kpart = blockIdx.x >> 9;
    int m0 = mt * 16;
    int sr = tid >> 4, sc = (tid & 15) * 4;          // 16 threads/row

    // front-load the entire 16x1024 chunk: 16 f32x4 per thread
    const float* xp = x + (size_t)(m0 + sr) * DIN + kpart * 1024 + sc;
    f32x4 r[16];
    #pragma unroll
    for (int p = 0; p < 16; ++p) r[p] = *(const f32x4*)(xp + p * 64);

    #pragma unroll
    for (int p = 0; p < 16; ++p) {
        ushort4 h;
        h.x = f2bf(r[p][0]); h.y = f2bf(r[p][1]); h.z = f2bf(r[p][2]); h.w = f2bf(r[p][3]);
        *(ushort4*)&stage[sr][p * 64 + sc] = h;
    }
    __syncthreads();

    // wave owns K-slice of 256: 8 steps x 4 MFMA
    f32x4 acc0 = {0.f, 0.f, 0.f, 0.f};
    f32x4 acc1 = acc0, acc2 = acc0, acc3 = acc0;
    #pragma unroll
    for (int s = 0; s < 8; ++s) {
        bf16x8 af = *(const bf16x8*)&stage[row][wid * 256 + s * 32 + kq * 8];
        int ks = kpart * 32 + wid * 8 + s;
        const unsigned short* ap = Afrag + (size_t)(ks << 2) * 512 + lane8;
        acc0 = MFMA16(af, *(const bf16x8*)(ap), acc0);
        acc1 = MFMA16(af, *(const bf16x8*)(ap + 512), acc1);
        acc2 = MFMA16(af, *(const bf16x8*)(ap + 1024), acc2);
        acc3 = MFMA16(af, *(const bf16x8*)(ap + 1536), acc3);
    }
    __syncthreads();                                  // stage reads done

    int mb = kq * 4;                                  // C: row=(lane>>4)*4+reg
    #pragma unroll
    for (int rg = 0; rg < 4; ++rg) {
        red[wid][(mb + rg) * 64 + row]      = acc0[rg];
        red[wid][(mb + rg) * 64 + 16 + row] = acc1[rg];
        red[wid][(mb + rg) * 64 + 32 + row] = acc2[rg];
        red[wid][(mb + rg) * 64 + 48 + row] = acc3[rg];
    }
    __syncthreads();
    #pragma unroll
    for (int e = tid; e < 1024; e += 256) {
        float s = red[0][e] + red[1][e] + red[2][e] + red[3][e];
        pxa[(size_t)kpart * M_TOT * RNK + (size_t)(m0 + (e >> 6)) * RNK + (e & 63)] = s;
    }
}

// k1_fin: xa frag-major bf16 <- sum of 4 f32 partials. 512 blocks x 256 thr.
__global__ __launch_bounds__(256) void k1_fin(const float* __restrict__ pxa,
                                              unsigned short* __restrict__ xafrag) {
    int tid = threadIdx.x;
    int mt = blockIdx.x;
    int e0 = tid * 4;
    size_t o = (size_t)(mt * 16 + (e0 >> 6)) * RNK + (e0 & 63);
    f32x4 s0 = *(const f32x4*)(pxa + o);
    f32x4 s1 = *(const f32x4*)(pxa + (size_t)M_TOT * RNK + o);
    f32x4 s2 = *(const f32x4*)(pxa + 2 * (size_t)M_TOT * RNK + o);
    f32x4 s3 = *(const f32x4*)(pxa + 3 * (size_t)M_TOT * RNK + o);
    int ml = e0 >> 6, r0 = e0 & 63;
    ushort4 h;
    h.x = f2bf(s0[0] + s1[0] + s2[0] + s3[0]);
    h.y = f2bf(s0[1] + s1[1] + s2[1] + s3[1]);
    h.z = f2bf(s0[2] + s1[2] + s2[2] + s3[2]);
    h.w = f2bf(s0[3] + s1[3] + s2[3] + s3[3]);
    *(ushort4*)&xafrag[((size_t)(mt * 2 + (r0 >> 5))) * 512 +
                       ((((r0 >> 3) & 3) << 4) + ml) * 8 + (r0 & 7)] = h;
}

// ---------------------------------------------------------------------------
// k2_norm: partial squared row-norms of (bw + 2*B@A) over 16o x 512i chunk.
// Grid: 256 o-tiles x 8 i-parts = 2048 blocks, 256 threads.
// ---------------------------------------------------------------------------
__global__ __launch_bounds__(256, 4) void k2_norm(const float* __restrict__ bw,
                                                  const unsigned short* __restrict__ Bfrag,
                                                  const unsigned short* __restrict__ Atfrag,
                                                  float* __restrict__ pn) {
    __shared__ __align__(16) char smem[33280];
    float (*stagef)[516] = (float (*)[516])smem;     // 33 KB
    float (*part)[16] = (float (*)[16])(smem + 33024);
    int tid = threadIdx.x;
    int wid = tid >> 6, lane = tid & 63;
    int row = lane & 15, kq = lane >> 4;
    int lane8 = lane * 8;
    int ot = blockIdx.x & 255, ipart = blockIdx.x >> 8;
    int o0 = ot * 16;
    int sr = tid >> 4, sc = (tid & 15) * 4;

    // front-load the entire 16x512 chunk: 8 f32x4 per thread
    const float* bwp = bw + (size_t)(o0 + sr) * DIN + ipart * 512 + sc;
    f32x4 q[8];
    #pragma unroll
    for (int p = 0; p < 8; ++p) q[p] = *(const f32x4*)(bwp + p * 64);

    bf16x8 b0 = *(const bf16x8*)(Bfrag + (size_t)(ot * 2) * 512 + lane8);
    bf16x8 b1 = *(const bf16x8*)(Bfrag + (size_t)(ot * 2 + 1) * 512 + lane8);

    #pragma unroll
    for (int p = 0; p < 8; ++p) *(f32x4*)&stagef[sr][p * 64 + sc] = q[p];
    __syncthreads();

    // wave owns i-slice of 128: 8 groups of 16 i
    f32x4 nacc = {0.f, 0.f, 0.f, 0.f};
    #pragma unroll
    for (int g = 0; g < 8; ++g) {
        int iloc = wid * 128 + g * 16;
        int it = (ipart * 512 + iloc) >> 4;
        const unsigned short* atp = Atfrag + (size_t)(it * 2) * 512 + lane8;
        bf16x8 a0 = *(const bf16x8*)(atp);
        bf16x8 a1 = *(const bf16x8*)(atp + 512);
        f32x4 d = {0.f, 0.f, 0.f, 0.f};
        d = MFMA16(a0, b0, d);                       // lane: delta[o=o0+row][i=iloc+kq*4+rg]
        d = MFMA16(a1, b1, d);
        f32x4 wv = *(const f32x4*)&stagef[row][iloc + kq * 4];
        #pragma unroll
        for (int rg = 0; rg < 4; ++rg) {
            float w = wv[rg] + 2.0f * d[rg];
            nacc[rg] += w * w;
        }
    }
    float ns = nacc[0] + nacc[1] + nacc[2] + nacc[3];
    ns += __shfl_xor(ns, 16, 64);
    ns += __shfl_xor(ns, 32, 64);
    if (kq == 0) part[wid][row] = ns;
    __syncthreads();
    if (tid < 16)
        pn[ipart * DOUT + o0 + tid] =
            part[0][tid] + part[1][tid] + part[2][tid] + part[3][tid];
}

// k2b: mscale[o] = mag[o] / (sqrt(sum_p pn[p][o]) + eps). 16 blocks x 256 thr.
__global__ __launch_bounds__(256) void k2b_scale(const float* __restrict__ pn,
                                                 const float* __restrict__ mag,
                                                 float* __restrict__ mscale) {
    int o = blockIdx.x * 256 + threadIdx.x;
    float n2 = 0.f;
    #pragma unroll
    for (int p = 0; p < 8; ++p) n2 += pn[p * DOUT + o];
    mscale[o] = mag[o] / (sqrtf(n2) + 1e-8f);
}

// ---------------------------------------------------------------------------
// kB: out = (base_output + 2 * xa @ lora_B^T) * mscale   (exact r7 version)
// Two 16m x 256n tiles per block; all fragments coalesced (frag-major).
// ---------------------------------------------------------------------------
__global__ __launch_bounds__(256) void kB(const float* __restrict__ base,
                                          const unsigned short* __restrict__ xafrag,
                                          const unsigned short* __restrict__ Bfrag,
                                          const float* __restrict__ mscale,
                                          float* __restrict__ out) {
    __shared__ float dls[32][260];                   // 33.3 KB, +4 pad
    int tid = threadIdx.x;
    int wid = tid >> 6, lane = tid & 63;
    int row = lane & 15, kq = lane >> 4;
    int m0 = blockIdx.x * 32;
    int n0 = blockIdx.y * 256;
    int col = n0 + lane * 4;
    int lane8 = lane * 8;

    // issue epilogue loads early: they retire under the MFMA phase
    f32x4 bpre[2][4];
    #pragma unroll
    for (int h = 0; h < 2; ++h)
        #pragma unroll
        for (int r = 0; r < 4; ++r)
            bpre[h][r] = __builtin_nontemporal_load(
                (const f32x4*)(base + (size_t)(m0 + h * 16 + wid * 4 + r) * DOUT + col));
    f32x4 msv = *(const f32x4*)(mscale + col);

    // MFMA phase: delta = xa @ B^T for two 16x256 tiles
    bf16x8 xb0[2], xb1[2];
    #pragma unroll
    for (int h = 0; h < 2; ++h) {
        size_t mt = (size_t)(blockIdx.x * 2 + h);
        xb0[h] = *(const bf16x8*)(xafrag + (mt * 2) * 512 + lane8);
        xb1[h] = *(const bf16x8*)(xafrag + (mt * 2 + 1) * 512 + lane8);
    }

    #pragma unroll
    for (int nt = 0; nt < 4; ++nt) {
        size_t ntg = (size_t)((n0 + wid * 64 + nt * 16) >> 4);
        bf16x8 a0 = *(const bf16x8*)(Bfrag + (ntg * 2) * 512 + lane8);
        bf16x8 a1 = *(const bf16x8*)(Bfrag + (ntg * 2 + 1) * 512 + lane8);
        #pragma unroll
        for (int h = 0; h < 2; ++h) {
            f32x4 acc = {0.f, 0.f, 0.f, 0.f};
            acc = MFMA16(a0, xb0[h], acc);           // lane: delta[m=row][nloc=kq*4+rg]
            acc = MFMA16(a1, xb1[h], acc);
            *(f32x4*)&dls[h * 16 + row][wid * 64 + nt * 16 + kq * 4] = acc;
        }
    }
    __syncthreads();

    #pragma unroll
    for (int h = 0; h < 2; ++h)
        #pragma unroll
        for (int r = 0; r < 4; ++r) {
            int m = h * 16 + wid * 4 + r;
            f32x4 d = *(const f32x4*)&dls[m][lane * 4];
            size_t gidx = (size_t)(m0 + m) * DOUT + col;
            f32x4 o;
            #pragma unroll
            for (int j = 0; j < 4; ++j) o[j] = (bpre[h][r][j] + 2.0f * d[j]) * msv[j];
            __builtin_nontemporal_store(o, (f32x4*)(out + gidx));
        }
}

extern "C" void kernel_launch(void* const* d_in, const int* in_sizes, int n_in,
                              void* d_out, int out_size, void* d_ws, size_t ws_size,
                              hipStream_t stream) {
    const float* x    = (const float*)d_in[0];   // [2,4096,4096]
    const float* base = (const float*)d_in[1];   // [2,4096,4096]
    const float* bw   = (const float*)d_in[2];   // [4096,4096]
    const float* lA   = (const float*)d_in[3];   // [64,4096]
    const float* lB   = (const float*)d_in[4];   // [4096,64]
    const float* mag  = (const float*)d_in[5];   // [4096]
    float* out = (float*)d_out;

    char* ws = (char*)d_ws;
    unsigned short* Afrag  = (unsigned short*)(ws);                  // 512 KB
    unsigned short* Atfrag = (unsigned short*)(ws + (512u << 10));   // 512 KB
    unsigned short* Bfrag  = (unsigned short*)(ws + (1024u << 10));  // 512 KB
    unsigned short* xafrag = (unsigned short*)(ws + (1536u << 10));  // 1 MB
    float*          pxa    = (float*)(ws + (2560u << 10));           // 8 MB
    float*          pn     = (float*)(ws + (10752u << 10));          // 128 KB
    float*          msc    = (float*)(ws + (10880u << 10));          // 16 KB

    hipLaunchKernelGGL(k_prep, dim3(1024), dim3(256), 0, stream, lA, lB, Afrag, Atfrag, Bfrag);
    hipLaunchKernelGGL(k1_xa, dim3(2048), dim3(256), 0, stream, x, Afrag, pxa);
    hipLaunchKernelGGL(k2_norm, dim3(2048), dim3(256), 0, stream, bw, Bfrag, Atfrag, pn);
    hipLaunchKernelGGL(k1_fin, dim3(512), dim3(256), 0, stream, pxa, xafrag);
    hipLaunchKernelGGL(k2b_scale, dim3(DOUT / 256), dim3(256), 0, stream, pn, mag, msc);
    hipLaunchKernelGGL(kB, dim3(M_TOT / 32, DOUT / 256), dim3(256), 0, stream,
                       base, xafrag, Bfrag, msc, out);
}

// Round 10
// 119.293 us; speedup vs baseline: 1.1299x; 1.0395x over previous
//
#include <hip/hip_runtime.h>
#include <math.h>

typedef __bf16 bf16x8 __attribute__((ext_vector_type(8)));
typedef float f32x4 __attribute__((ext_vector_type(4)));

#define MFMA16(a, b, c) __builtin_amdgcn_mfma_f32_16x16x32_bf16(a, b, c, 0, 0, 0)

static constexpr int M_TOT = 8192;   // B*S
static constexpr int DIN = 4096;
static constexpr int DOUT = 4096;
static constexpr int RNK = 64;

__device__ inline unsigned short f2bf(float f) {
    union { float f; unsigned u; } v; v.f = f;
    unsigned r = v.u + 0x7FFFu + ((v.u >> 16) & 1u);   // round-to-nearest-even
    return (unsigned short)(r >> 16);
}

// ---------------------------------------------------------------------------
// Fragment-major layout: block (tile,slice) holds the 64 lanes' bf16x8
// contiguously; every wave fragment load = one coalesced 1 KB instruction.
// ---------------------------------------------------------------------------
__global__ __launch_bounds__(256) void k_prep(const float* __restrict__ A,
                                              const float* __restrict__ B,
                                              unsigned short* __restrict__ Afrag,
                                              unsigned short* __restrict__ Atfrag,
                                              unsigned short* __restrict__ Bfrag) {
    int i = blockIdx.x * 256 + threadIdx.x;          // 0 .. 262143
    unsigned short ab = f2bf(A[i]);
    int n = i >> 12, k = i & 4095;                   // A[n][k]
    Afrag[(((k >> 5) << 2) + (n >> 4)) * 512 +
          ((((k >> 3) & 3) << 4) + (n & 15)) * 8 + (k & 7)] = ab;
    Atfrag[(((k >> 4) << 1) + (n >> 5)) * 512 +
           ((((n >> 3) & 3) << 4) + (k & 15)) * 8 + (n & 7)] = ab;
    unsigned short bb = f2bf(B[i]);
    int o = i >> 6, r = i & 63;
    Bfrag[(((o >> 4) << 1) + (r >> 5)) * 512 +
          ((((r >> 3) & 3) << 4) + (o & 15)) * 8 + (r & 7)] = bb;
}

// ---------------------------------------------------------------------------
// k1_xa: partial xa = x @ lora_A^T over a 16m x 2048K half-row, processed as
// 4 pipelined chunks of 512 k. Schedule per chunk (single LDS buffer):
//   barrier -> ds_write(c) -> barrier(drains nothing) -> issue loads(c+1)
//   -> MFMA(c)   [loads retire under MFMA; next barrier's vmcnt-drain is
//                 hidden behind the ~1000cy compute/L2 phase]
// Grid: 512 m-tiles x 2 K-halves = 1024 blocks, 256 threads.
// ---------------------------------------------------------------------------
__global__ __launch_bounds__(256) void k1_xa(const float* __restrict__ x,
                                             const unsigned short* __restrict__ Afrag,
                                             float* __restrict__ pxa) {
    __shared__ __align__(16) char smem[16640];
    unsigned short (*stage)[520] = (unsigned short (*)[520])smem;  // 16.6 KB
    float (*red)[1024] = (float (*)[1024])smem;                    // 16 KB (aliases)
    int tid = threadIdx.x;
    int wid = tid >> 6, lane = tid & 63;
    int row = lane & 15, kq = lane >> 4;
    int lane8 = lane * 8;
    int mt = blockIdx.x & 511, kpart = blockIdx.x >> 9;
    int m0 = mt * 16;
    int sr = tid >> 4, sc = (tid & 15) * 4;          // staging: 16 threads/row

    const float* xp = x + (size_t)(m0 + sr) * DIN + kpart * 2048 + sc;

    // prologue: chunk 0 into regs
    f32x4 r[8];
    #pragma unroll
    for (int p = 0; p < 8; ++p) r[p] = *(const f32x4*)(xp + p * 64);

    f32x4 acc0 = {0.f, 0.f, 0.f, 0.f};
    f32x4 acc1 = acc0, acc2 = acc0, acc3 = acc0;

    for (int c = 0; c < 4; ++c) {                    // chunks of 512 k
        __syncthreads();                             // prev MFMA done with stage
        #pragma unroll
        for (int p = 0; p < 8; ++p) {
            ushort4 h;
            h.x = f2bf(r[p][0]); h.y = f2bf(r[p][1]);
            h.z = f2bf(r[p][2]); h.w = f2bf(r[p][3]);
            *(ushort4*)&stage[sr][p * 64 + sc] = h;
        }
        __syncthreads();                             // stage visible; 0 loads in flight
        if (c < 3) {                                 // issue next chunk AFTER the barrier
            const float* nx = xp + (c + 1) * 512;
            #pragma unroll
            for (int p = 0; p < 8; ++p) r[p] = *(const f32x4*)(nx + p * 64);
        }
        // MFMA phase: wave owns k-slice of 128 within the chunk
        #pragma unroll
        for (int s = 0; s < 4; ++s) {
            bf16x8 af = *(const bf16x8*)&stage[row][wid * 128 + s * 32 + kq * 8];
            int ks = (kpart * 2048 + c * 512 + wid * 128 + s * 32) >> 5;
            const unsigned short* ap = Afrag + (size_t)(ks << 2) * 512 + lane8;
            acc0 = MFMA16(af, *(const bf16x8*)(ap), acc0);
            acc1 = MFMA16(af, *(const bf16x8*)(ap + 512), acc1);
            acc2 = MFMA16(af, *(const bf16x8*)(ap + 1024), acc2);
            acc3 = MFMA16(af, *(const bf16x8*)(ap + 1536), acc3);
        }
    }
    __syncthreads();                                 // stage reads done; red aliases

    int mb = kq * 4;                                 // C: row=(lane>>4)*4+reg
    #pragma unroll
    for (int rg = 0; rg < 4; ++rg) {
        red[wid][(mb + rg) * 64 + row]      = acc0[rg];
        red[wid][(mb + rg) * 64 + 16 + row] = acc1[rg];
        red[wid][(mb + rg) * 64 + 32 + row] = acc2[rg];
        red[wid][(mb + rg) * 64 + 48 + row] = acc3[rg];
    }
    __syncthreads();
    #pragma unroll
    for (int e = tid; e < 1024; e += 256) {
        float s = red[0][e] + red[1][e] + red[2][e] + red[3][e];
        pxa[(size_t)kpart * M_TOT * RNK + (size_t)(m0 + (e >> 6)) * RNK + (e & 63)] = s;
    }
}

// k1_fin: xa frag-major bf16 <- sum of 2 f32 partials. 512 blocks x 256 thr.
__global__ __launch_bounds__(256) void k1_fin(const float* __restrict__ pxa,
                                              unsigned short* __restrict__ xafrag) {
    int tid = threadIdx.x;
    int mt = blockIdx.x;
    int e0 = tid * 4;
    size_t o = (size_t)(mt * 16 + (e0 >> 6)) * RNK + (e0 & 63);
    f32x4 s0 = *(const f32x4*)(pxa + o);
    f32x4 s1 = *(const f32x4*)(pxa + (size_t)M_TOT * RNK + o);
    int ml = e0 >> 6, r0 = e0 & 63;
    ushort4 h;
    h.x = f2bf(s0[0] + s1[0]);
    h.y = f2bf(s0[1] + s1[1]);
    h.z = f2bf(s0[2] + s1[2]);
    h.w = f2bf(s0[3] + s1[3]);
    *(ushort4*)&xafrag[((size_t)(mt * 2 + (r0 >> 5))) * 512 +
                       ((((r0 >> 3) & 3) << 4) + ml) * 8 + (r0 & 7)] = h;
}

// ---------------------------------------------------------------------------
// k2_norm: partial squared row-norms of (bw + 2*B@A) over 16o x 1024i,
// processed as 4 pipelined chunks of 256 i (same schedule as k1_xa).
// Grid: 256 o-tiles x 4 i-quarters = 1024 blocks, 256 threads.
// ---------------------------------------------------------------------------
__global__ __launch_bounds__(256) void k2_norm(const float* __restrict__ bw,
                                               const unsigned short* __restrict__ Bfrag,
                                               const unsigned short* __restrict__ Atfrag,
                                               float* __restrict__ pn) {
    __shared__ __align__(16) char smem[16896];
    float (*stagef)[260] = (float (*)[260])smem;     // 16.6 KB
    float (*part)[16] = (float (*)[16])(smem + 16640);
    int tid = threadIdx.x;
    int wid = tid >> 6, lane = tid & 63;
    int row = lane & 15, kq = lane >> 4;
    int lane8 = lane * 8;
    int ot = blockIdx.x & 255, ipart = blockIdx.x >> 8;
    int o0 = ot * 16;
    int sr = tid >> 4, sc = (tid & 15) * 4;

    const float* bwp = bw + (size_t)(o0 + sr) * DIN + ipart * 1024 + sc;

    // prologue: chunk 0 into regs
    f32x4 q[4];
    #pragma unroll
    for (int p = 0; p < 4; ++p) q[p] = *(const f32x4*)(bwp + p * 64);

    bf16x8 b0 = *(const bf16x8*)(Bfrag + (size_t)(ot * 2) * 512 + lane8);
    bf16x8 b1 = *(const bf16x8*)(Bfrag + (size_t)(ot * 2 + 1) * 512 + lane8);

    f32x4 nacc = {0.f, 0.f, 0.f, 0.f};

    for (int c = 0; c < 4; ++c) {                    // chunks of 256 i
        __syncthreads();
        #pragma unroll
        for (int p = 0; p < 4; ++p) *(f32x4*)&stagef[sr][p * 64 + sc] = q[p];
        __syncthreads();                             // visible; 0 loads in flight
        if (c < 3) {
            const float* nb = bwp + (c + 1) * 256;
            #pragma unroll
            for (int p = 0; p < 4; ++p) q[p] = *(const f32x4*)(nb + p * 64);
        }
        // wave owns i-slice of 64: 4 groups of 16 i
        #pragma unroll
        for (int g = 0; g < 4; ++g) {
            int iloc = wid * 64 + g * 16;
            int it = (ipart * 1024 + c * 256 + iloc) >> 4;
            const unsigned short* atp = Atfrag + (size_t)(it * 2) * 512 + lane8;
            bf16x8 a0 = *(const bf16x8*)(atp);
            bf16x8 a1 = *(const bf16x8*)(atp + 512);
            f32x4 d = {0.f, 0.f, 0.f, 0.f};
            d = MFMA16(a0, b0, d);                   // lane: delta[o=o0+row][i=iloc+kq*4+rg]
            d = MFMA16(a1, b1, d);
            f32x4 wv = *(const f32x4*)&stagef[row][iloc + kq * 4];
            #pragma unroll
            for (int rg = 0; rg < 4; ++rg) {
                float w = wv[rg] + 2.0f * d[rg];
                nacc[rg] += w * w;
            }
        }
    }
    float ns = nacc[0] + nacc[1] + nacc[2] + nacc[3];
    ns += __shfl_xor(ns, 16, 64);
    ns += __shfl_xor(ns, 32, 64);
    if (kq == 0) part[wid][row] = ns;
    __syncthreads();
    if (tid < 16)
        pn[ipart * DOUT + o0 + tid] =
            part[0][tid] + part[1][tid] + part[2][tid] + part[3][tid];
}

// k2b: mscale[o] = mag[o] / (sqrt(sum_p pn[p][o]) + eps). 16 blocks x 256 thr.
__global__ __launch_bounds__(256) void k2b_scale(const float* __restrict__ pn,
                                                 const float* __restrict__ mag,
                                                 float* __restrict__ mscale) {
    int o = blockIdx.x * 256 + threadIdx.x;
    float n2 = 0.f;
    #pragma unroll
    for (int p = 0; p < 4; ++p) n2 += pn[p * DOUT + o];
    mscale[o] = mag[o] / (sqrtf(n2) + 1e-8f);
}

// ---------------------------------------------------------------------------
// kB: out = (base_output + 2 * xa @ lora_B^T) * mscale   (proven r7/r9 form)
// ---------------------------------------------------------------------------
__global__ __launch_bounds__(256) void kB(const float* __restrict__ base,
                                          const unsigned short* __restrict__ xafrag,
                                          const unsigned short* __restrict__ Bfrag,
                                          const float* __restrict__ mscale,
                                          float* __restrict__ out) {
    __shared__ float dls[32][260];                   // 33.3 KB, +4 pad
    int tid = threadIdx.x;
    int wid = tid >> 6, lane = tid & 63;
    int row = lane & 15, kq = lane >> 4;
    int m0 = blockIdx.x * 32;
    int n0 = blockIdx.y * 256;
    int col = n0 + lane * 4;
    int lane8 = lane * 8;

    // issue epilogue loads early: they retire under the MFMA phase
    f32x4 bpre[2][4];
    #pragma unroll
    for (int h = 0; h < 2; ++h)
        #pragma unroll
        for (int r = 0; r < 4; ++r)
            bpre[h][r] = __builtin_nontemporal_load(
                (const f32x4*)(base + (size_t)(m0 + h * 16 + wid * 4 + r) * DOUT + col));
    f32x4 msv = *(const f32x4*)(mscale + col);

    // MFMA phase: delta = xa @ B^T for two 16x256 tiles
    bf16x8 xb0[2], xb1[2];
    #pragma unroll
    for (int h = 0; h < 2; ++h) {
        size_t mt = (size_t)(blockIdx.x * 2 + h);
        xb0[h] = *(const bf16x8*)(xafrag + (mt * 2) * 512 + lane8);
        xb1[h] = *(const bf16x8*)(xafrag + (mt * 2 + 1) * 512 + lane8);
    }

    #pragma unroll
    for (int nt = 0; nt < 4; ++nt) {
        size_t ntg = (size_t)((n0 + wid * 64 + nt * 16) >> 4);
        bf16x8 a0 = *(const bf16x8*)(Bfrag + (ntg * 2) * 512 + lane8);
        bf16x8 a1 = *(const bf16x8*)(Bfrag + (ntg * 2 + 1) * 512 + lane8);
        #pragma unroll
        for (int h = 0; h < 2; ++h) {
            f32x4 acc = {0.f, 0.f, 0.f, 0.f};
            acc = MFMA16(a0, xb0[h], acc);           // lane: delta[m=row][nloc=kq*4+rg]
            acc = MFMA16(a1, xb1[h], acc);
            *(f32x4*)&dls[h * 16 + row][wid * 64 + nt * 16 + kq * 4] = acc;
        }
    }
    __syncthreads();

    #pragma unroll
    for (int h = 0; h < 2; ++h)
        #pragma unroll
        for (int r = 0; r < 4; ++r) {
            int m = h * 16 + wid * 4 + r;
            f32x4 d = *(const f32x4*)&dls[m][lane * 4];
            size_t gidx = (size_t)(m0 + m) * DOUT + col;
            f32x4 o;
            #pragma unroll
            for (int j = 0; j < 4; ++j) o[j] = (bpre[h][r][j] + 2.0f * d[j]) * msv[j];
            __builtin_nontemporal_store(o, (f32x4*)(out + gidx));
        }
}

extern "C" void kernel_launch(void* const* d_in, const int* in_sizes, int n_in,
                              void* d_out, int out_size, void* d_ws, size_t ws_size,
                              hipStream_t stream) {
    const float* x    = (const float*)d_in[0];   // [2,4096,4096]
    const float* base = (const float*)d_in[1];   // [2,4096,4096]
    const float* bw   = (const float*)d_in[2];   // [4096,4096]
    const float* lA   = (const float*)d_in[3];   // [64,4096]
    const float* lB   = (const float*)d_in[4];   // [4096,64]
    const float* mag  = (const float*)d_in[5];   // [4096]
    float* out = (float*)d_out;

    char* ws = (char*)d_ws;
    unsigned short* Afrag  = (unsigned short*)(ws);                  // 512 KB
    unsigned short* Atfrag = (unsigned short*)(ws + (512u << 10));   // 512 KB
    unsigned short* Bfrag  = (unsigned short*)(ws + (1024u << 10));  // 512 KB
    unsigned short* xafrag = (unsigned short*)(ws + (1536u << 10));  // 1 MB
    float*          pxa    = (float*)(ws + (2560u << 10));           // 4 MB
    float*          pn     = (float*)(ws + (6656u << 10));           // 64 KB
    float*          msc    = (float*)(ws + (6720u << 10));           // 16 KB

    hipLaunchKernelGGL(k_prep, dim3(1024), dim3(256), 0, stream, lA, lB, Afrag, Atfrag, Bfrag);
    hipLaunchKernelGGL(k1_xa, dim3(1024), dim3(256), 0, stream, x, Afrag, pxa);
    hipLaunchKernelGGL(k2_norm, dim3(1024), dim3(256), 0, stream, bw, Bfrag, Atfrag, pn);
    hipLaunchKernelGGL(k1_fin, dim3(512), dim3(256), 0, stream, pxa, xafrag);
    hipLaunchKernelGGL(k2b_scale, dim3(DOUT / 256), dim3(256), 0, stream, pn, mag, msc);
    hipLaunchKernelGGL(kB, dim3(M_TOT / 32, DOUT / 256), dim3(256), 0, stream,
                       base, xafrag, Bfrag, msc, out);
}

// Round 11
// 113.401 us; speedup vs baseline: 1.1887x; 1.0520x over previous
//
#include <hip/hip_runtime.h>
#include <math.h>

typedef __bf16 bf16x8 __attribute__((ext_vector_type(8)));
typedef float f32x4 __attribute__((ext_vector_type(4)));

#define MFMA16(a, b, c) __builtin_amdgcn_mfma_f32_16x16x32_bf16(a, b, c, 0, 0, 0)

static constexpr int M_TOT = 8192;   // B*S
static constexpr int DIN = 4096;
static constexpr int DOUT = 4096;
static constexpr int RNK = 64;

__device__ inline unsigned short f2bf(float f) {
    union { float f; unsigned u; } v; v.f = f;
    unsigned r = v.u + 0x7FFFu + ((v.u >> 16) & 1u);   // round-to-nearest-even
    return (unsigned short)(r >> 16);
}

// async global->LDS, 16 B per lane; LDS dest = wave-uniform base + lane*16
__device__ inline void gload_lds16(const float* g, char* lds_base) {
    __builtin_amdgcn_global_load_lds(
        (const __attribute__((address_space(1))) void*)g,
        (__attribute__((address_space(3))) void*)lds_base, 16, 0, 0);
}

// ---------------------------------------------------------------------------
// Fragment-major layout (unchanged): block (tile,slice) holds the 64 lanes'
// bf16x8 contiguously; every wave fragment load = one coalesced 1 KB instr.
// ---------------------------------------------------------------------------
__global__ __launch_bounds__(256) void k_prep(const float* __restrict__ A,
                                              const float* __restrict__ B,
                                              unsigned short* __restrict__ Afrag,
                                              unsigned short* __restrict__ Atfrag,
                                              unsigned short* __restrict__ Bfrag) {
    int i = blockIdx.x * 256 + threadIdx.x;          // 0 .. 262143
    unsigned short ab = f2bf(A[i]);
    int n = i >> 12, k = i & 4095;                   // A[n][k]
    Afrag[(((k >> 5) << 2) + (n >> 4)) * 512 +
          ((((k >> 3) & 3) << 4) + (n & 15)) * 8 + (k & 7)] = ab;
    Atfrag[(((k >> 4) << 1) + (n >> 5)) * 512 +
           ((((n >> 3) & 3) << 4) + (k & 15)) * 8 + (n & 7)] = ab;
    unsigned short bb = f2bf(B[i]);
    int o = i >> 6, r = i & 63;
    Bfrag[(((o >> 4) << 1) + (r >> 5)) * 512 +
          ((((r >> 3) & 3) << 4) + (o & 15)) * 8 + (r & 7)] = bb;
}

// ---------------------------------------------------------------------------
// k1_xa: partial xa = x @ lora_A^T over 16m x 2048K, 8 chunks of 16x256 f32.
// Per chunk: {stage(next) via global_load_lds + Afrag(next) into regs} ->
// compute(cur: LDS + regs only, NO vmem) -> one barrier (the only vmcnt
// drain, overlapped by the in-flight next-chunk loads). LDS linear (m104),
// source pre-swizzled by (chunk16^((row&7)<<4)) (m173), XOR on read side.
// Grid: 512 m-tiles x 2 K-halves = 1024 blocks, 256 threads.
// ---------------------------------------------------------------------------
__global__ __launch_bounds__(256) void k1_xa(const float* __restrict__ x,
                                             const unsigned short* __restrict__ Afrag,
                                             float* __restrict__ pxa) {
    __shared__ __align__(16) char smem[32768];       // buf0 16K | buf1 16K
    char* buf0 = smem;
    char* buf1 = smem + 16384;
    float (*red)[1024] = (float (*)[1024])smem;      // 16 KB, aliases buf0 after loop
    int tid = threadIdx.x;
    int wid = tid >> 6, lane = tid & 63;
    int row = lane & 15, kq = lane >> 4;
    int lane8 = lane * 8;
    int mt = blockIdx.x & 511, kpart = blockIdx.x >> 9;
    int m0 = mt * 16;
    int swzr = (row & 7) << 4;
    const float* xbase = x + (size_t)m0 * DIN + kpart * 2048;

    f32x4 acc0 = {0.f, 0.f, 0.f, 0.f};
    f32x4 acc1 = acc0, acc2 = acc0, acc3 = acc0;
    bf16x8 setA[8], setB[8];

    // stage chunk c (16 rows x 256 f32) into buf; wave w covers rows w*4..w*4+3
    auto STAGE = [&](char* buf, int c) {
        #pragma unroll
        for (int j = 0; j < 4; ++j) {
            int r = wid * 4 + j;
            int srcb = (lane * 16) ^ ((r & 7) << 4);   // pre-swizzled source byte
            const float* g = xbase + (size_t)r * DIN + c * 256 + (srcb >> 2);
            gload_lds16(g, buf + r * 1024);
        }
    };
    // prefetch the 8 Afrag fragments chunk c's compute needs (regs, L2-resident)
    auto AFRAG = [&](bf16x8* set, int c) {
        #pragma unroll
        for (int s = 0; s < 2; ++s) {
            int ks = kpart * 64 + c * 8 + wid * 2 + s;
            const unsigned short* ap = Afrag + (size_t)ks * 2048 + lane8;
            set[s * 4 + 0] = *(const bf16x8*)(ap);
            set[s * 4 + 1] = *(const bf16x8*)(ap + 512);
            set[s * 4 + 2] = *(const bf16x8*)(ap + 1024);
            set[s * 4 + 3] = *(const bf16x8*)(ap + 1536);
        }
    };
    // compute chunk from LDS + register fragments only (no global loads)
    auto COMPUTE = [&](const char* buf, const bf16x8* set) {
        #pragma unroll
        for (int s = 0; s < 2; ++s) {
            int kbyte = wid * 256 + s * 128 + kq * 32;
            f32x4 xlo = *(const f32x4*)(buf + row * 1024 + ((kbyte) ^ swzr));
            f32x4 xhi = *(const f32x4*)(buf + row * 1024 + ((kbyte + 16) ^ swzr));
            bf16x8 af;
            #pragma unroll
            for (int j = 0; j < 4; ++j) {
                af[j] = (__bf16)xlo[j];
                af[j + 4] = (__bf16)xhi[j];
            }
            acc0 = MFMA16(af, set[s * 4 + 0], acc0);
            acc1 = MFMA16(af, set[s * 4 + 1], acc1);
            acc2 = MFMA16(af, set[s * 4 + 2], acc2);
            acc3 = MFMA16(af, set[s * 4 + 3], acc3);
        }
    };

    STAGE(buf0, 0); AFRAG(setA, 0);
    __syncthreads();                                  // drain batch 0
    #pragma unroll
    for (int c = 0; c < 8; c += 2) {
        if (c + 1 < 8) { STAGE(buf1, c + 1); AFRAG(setB, c + 1); }
        COMPUTE(buf0, setA);                          // no vmem waits inside
        __syncthreads();                              // drain batch c+1
        if (c + 2 < 8) { STAGE(buf0, c + 2); AFRAG(setA, c + 2); }
        if (c + 1 < 8) COMPUTE(buf1, setB);
        __syncthreads();                              // drain batch c+2
    }

    int mb = kq * 4;                                  // C: row=(lane>>4)*4+reg
    #pragma unroll
    for (int rg = 0; rg < 4; ++rg) {
        red[wid][(mb + rg) * 64 + row]      = acc0[rg];
        red[wid][(mb + rg) * 64 + 16 + row] = acc1[rg];
        red[wid][(mb + rg) * 64 + 32 + row] = acc2[rg];
        red[wid][(mb + rg) * 64 + 48 + row] = acc3[rg];
    }
    __syncthreads();
    #pragma unroll
    for (int e = tid; e < 1024; e += 256) {
        float s = red[0][e] + red[1][e] + red[2][e] + red[3][e];
        pxa[(size_t)kpart * M_TOT * RNK + (size_t)(m0 + (e >> 6)) * RNK + (e & 63)] = s;
    }
}

// k1_fin: xa frag-major bf16 <- sum of 2 f32 partials. 512 blocks x 256 thr.
__global__ __launch_bounds__(256) void k1_fin(const float* __restrict__ pxa,
                                              unsigned short* __restrict__ xafrag) {
    int tid = threadIdx.x;
    int mt = blockIdx.x;
    int e0 = tid * 4;
    size_t o = (size_t)(mt * 16 + (e0 >> 6)) * RNK + (e0 & 63);
    f32x4 s0 = *(const f32x4*)(pxa + o);
    f32x4 s1 = *(const f32x4*)(pxa + (size_t)M_TOT * RNK + o);
    int ml = e0 >> 6, r0 = e0 & 63;
    ushort4 h;
    h.x = f2bf(s0[0] + s1[0]);
    h.y = f2bf(s0[1] + s1[1]);
    h.z = f2bf(s0[2] + s1[2]);
    h.w = f2bf(s0[3] + s1[3]);
    *(ushort4*)&xafrag[((size_t)(mt * 2 + (r0 >> 5))) * 512 +
                       ((((r0 >> 3) & 3) << 4) + ml) * 8 + (r0 & 7)] = h;
}

// ---------------------------------------------------------------------------
// k2_norm: partial squared row-norms of (bw + 2*B@A) over 16o x 1024i,
// 4 chunks of 16x256 f32, same async-2-phase template as k1_xa.
// Grid: 256 o-tiles x 4 i-quarters = 1024 blocks, 256 threads.
// ---------------------------------------------------------------------------
__global__ __launch_bounds__(256) void k2_norm(const float* __restrict__ bw,
                                               const unsigned short* __restrict__ Bfrag,
                                               const unsigned short* __restrict__ Atfrag,
                                               float* __restrict__ pn) {
    __shared__ __align__(16) char smem[32768];       // buf0 16K | buf1 16K
    __shared__ float part[4][16];
    char* buf0 = smem;
    char* buf1 = smem + 16384;
    int tid = threadIdx.x;
    int wid = tid >> 6, lane = tid & 63;
    int row = lane & 15, kq = lane >> 4;
    int lane8 = lane * 8;
    int ot = blockIdx.x & 255, ipart = blockIdx.x >> 8;
    int o0 = ot * 16;
    int swzr = (row & 7) << 4;
    const float* bwbase = bw + (size_t)o0 * DIN + ipart * 1024;

    bf16x8 b0 = *(const bf16x8*)(Bfrag + (size_t)(ot * 2) * 512 + lane8);
    bf16x8 b1 = *(const bf16x8*)(Bfrag + (size_t)(ot * 2 + 1) * 512 + lane8);

    f32x4 nacc = {0.f, 0.f, 0.f, 0.f};
    bf16x8 setA[8], setB[8];

    auto STAGE = [&](char* buf, int c) {
        #pragma unroll
        for (int j = 0; j < 4; ++j) {
            int r = wid * 4 + j;
            int srcb = (lane * 16) ^ ((r & 7) << 4);
            const float* g = bwbase + (size_t)r * DIN + c * 256 + (srcb >> 2);
            gload_lds16(g, buf + r * 1024);
        }
    };
    auto ATFRAG = [&](bf16x8* set, int c) {
        #pragma unroll
        for (int g = 0; g < 4; ++g) {
            int it = ipart * 64 + c * 16 + wid * 4 + g;
            const unsigned short* atp = Atfrag + (size_t)it * 1024 + lane8;
            set[g * 2]     = *(const bf16x8*)(atp);
            set[g * 2 + 1] = *(const bf16x8*)(atp + 512);
        }
    };
    auto COMPUTE = [&](const char* buf, const bf16x8* set) {
        #pragma unroll
        for (int g = 0; g < 4; ++g) {
            f32x4 d = {0.f, 0.f, 0.f, 0.f};
            d = MFMA16(set[g * 2], b0, d);           // delta[o=o0+row][i=..+kq*4+rg]
            d = MFMA16(set[g * 2 + 1], b1, d);
            int ibyte = wid * 256 + g * 64 + kq * 16;
            f32x4 wv = *(const f32x4*)(buf + row * 1024 + (ibyte ^ swzr));
            #pragma unroll
            for (int rg = 0; rg < 4; ++rg) {
                float w = wv[rg] + 2.0f * d[rg];
                nacc[rg] += w * w;
            }
        }
    };

    STAGE(buf0, 0); ATFRAG(setA, 0);
    __syncthreads();
    #pragma unroll
    for (int c = 0; c < 4; c += 2) {
        if (c + 1 < 4) { STAGE(buf1, c + 1); ATFRAG(setB, c + 1); }
        COMPUTE(buf0, setA);
        __syncthreads();
        if (c + 2 < 4) { STAGE(buf0, c + 2); ATFRAG(setA, c + 2); }
        if (c + 1 < 4) COMPUTE(buf1, setB);
        __syncthreads();
    }

    float ns = nacc[0] + nacc[1] + nacc[2] + nacc[3];
    ns += __shfl_xor(ns, 16, 64);
    ns += __shfl_xor(ns, 32, 64);
    if (kq == 0) part[wid][row] = ns;
    __syncthreads();
    if (tid < 16)
        pn[ipart * DOUT + o0 + tid] =
            part[0][tid] + part[1][tid] + part[2][tid] + part[3][tid];
}

// k2b: mscale[o] = mag[o] / (sqrt(sum_p pn[p][o]) + eps). 16 blocks x 256 thr.
__global__ __launch_bounds__(256) void k2b_scale(const float* __restrict__ pn,
                                                 const float* __restrict__ mag,
                                                 float* __restrict__ mscale) {
    int o = blockIdx.x * 256 + threadIdx.x;
    float n2 = 0.f;
    #pragma unroll
    for (int p = 0; p < 4; ++p) n2 += pn[p * DOUT + o];
    mscale[o] = mag[o] / (sqrtf(n2) + 1e-8f);
}

// ---------------------------------------------------------------------------
// kB: out = (base_output + 2 * xa @ lora_B^T) * mscale   (proven r7/r9 form)
// ---------------------------------------------------------------------------
__global__ __launch_bounds__(256) void kB(const float* __restrict__ base,
                                          const unsigned short* __restrict__ xafrag,
                                          const unsigned short* __restrict__ Bfrag,
                                          const float* __restrict__ mscale,
                                          float* __restrict__ out) {
    __shared__ float dls[32][260];                   // 33.3 KB, +4 pad
    int tid = threadIdx.x;
    int wid = tid >> 6, lane = tid & 63;
    int row = lane & 15, kq = lane >> 4;
    int m0 = blockIdx.x * 32;
    int n0 = blockIdx.y * 256;
    int col = n0 + lane * 4;
    int lane8 = lane * 8;

    f32x4 bpre[2][4];
    #pragma unroll
    for (int h = 0; h < 2; ++h)
        #pragma unroll
        for (int r = 0; r < 4; ++r)
            bpre[h][r] = __builtin_nontemporal_load(
                (const f32x4*)(base + (size_t)(m0 + h * 16 + wid * 4 + r) * DOUT + col));
    f32x4 msv = *(const f32x4*)(mscale + col);

    bf16x8 xb0[2], xb1[2];
    #pragma unroll
    for (int h = 0; h < 2; ++h) {
        size_t mt = (size_t)(blockIdx.x * 2 + h);
        xb0[h] = *(const bf16x8*)(xafrag + (mt * 2) * 512 + lane8);
        xb1[h] = *(const bf16x8*)(xafrag + (mt * 2 + 1) * 512 + lane8);
    }

    #pragma unroll
    for (int nt = 0; nt < 4; ++nt) {
        size_t ntg = (size_t)((n0 + wid * 64 + nt * 16) >> 4);
        bf16x8 a0 = *(const bf16x8*)(Bfrag + (ntg * 2) * 512 + lane8);
        bf16x8 a1 = *(const bf16x8*)(Bfrag + (ntg * 2 + 1) * 512 + lane8);
        #pragma unroll
        for (int h = 0; h < 2; ++h) {
            f32x4 acc = {0.f, 0.f, 0.f, 0.f};
            acc = MFMA16(a0, xb0[h], acc);           // lane: delta[m=row][nloc=kq*4+rg]
            acc = MFMA16(a1, xb1[h], acc);
            *(f32x4*)&dls[h * 16 + row][wid * 64 + nt * 16 + kq * 4] = acc;
        }
    }
    __syncthreads();

    #pragma unroll
    for (int h = 0; h < 2; ++h)
        #pragma unroll
        for (int r = 0; r < 4; ++r) {
            int m = h * 16 + wid * 4 + r;
            f32x4 d = *(const f32x4*)&dls[m][lane * 4];
            size_t gidx = (size_t)(m0 + m) * DOUT + col;
            f32x4 o;
            #pragma unroll
            for (int j = 0; j < 4; ++j) o[j] = (bpre[h][r][j] + 2.0f * d[j]) * msv[j];
            __builtin_nontemporal_store(o, (f32x4*)(out + gidx));
        }
}

extern "C" void kernel_launch(void* const* d_in, const int* in_sizes, int n_in,
                              void* d_out, int out_size, void* d_ws, size_t ws_size,
                              hipStream_t stream) {
    const float* x    = (const float*)d_in[0];   // [2,4096,4096]
    const float* base = (const float*)d_in[1];   // [2,4096,4096]
    const float* bw   = (const float*)d_in[2];   // [4096,4096]
    const float* lA   = (const float*)d_in[3];   // [64,4096]
    const float* lB   = (const float*)d_in[4];   // [4096,64]
    const float* mag  = (const float*)d_in[5];   // [4096]
    float* out = (float*)d_out;

    char* ws = (char*)d_ws;
    unsigned short* Afrag  = (unsigned short*)(ws);                  // 512 KB
    unsigned short* Atfrag = (unsigned short*)(ws + (512u << 10));   // 512 KB
    unsigned short* Bfrag  = (unsigned short*)(ws + (1024u << 10));  // 512 KB
    unsigned short* xafrag = (unsigned short*)(ws + (1536u << 10));  // 1 MB
    float*          pxa    = (float*)(ws + (2560u << 10));           // 4 MB
    float*          pn     = (float*)(ws + (6656u << 10));           // 64 KB
    float*          msc    = (float*)(ws + (6720u << 10));           // 16 KB

    hipLaunchKernelGGL(k_prep, dim3(1024), dim3(256), 0, stream, lA, lB, Afrag, Atfrag, Bfrag);
    hipLaunchKernelGGL(k1_xa, dim3(1024), dim3(256), 0, stream, x, Afrag, pxa);
    hipLaunchKernelGGL(k2_norm, dim3(1024), dim3(256), 0, stream, bw, Bfrag, Atfrag, pn);
    hipLaunchKernelGGL(k1_fin, dim3(512), dim3(256), 0, stream, pxa, xafrag);
    hipLaunchKernelGGL(k2b_scale, dim3(DOUT / 256), dim3(256), 0, stream, pn, mag, msc);
    hipLaunchKernelGGL(kB, dim3(M_TOT / 32, DOUT / 256), dim3(256), 0, stream,
                       base, xafrag, Bfrag, msc, out);
}

// Round 12
// 109.853 us; speedup vs baseline: 1.2270x; 1.0323x over previous
//
#include <hip/hip_runtime.h>
#include <math.h>

typedef __bf16 bf16x8 __attribute__((ext_vector_type(8)));
typedef float f32x4 __attribute__((ext_vector_type(4)));

#define MFMA16(a, b, c) __builtin_amdgcn_mfma_f32_16x16x32_bf16(a, b, c, 0, 0, 0)

static constexpr int M_TOT = 8192;   // B*S
static constexpr int DIN = 4096;
static constexpr int DOUT = 4096;
static constexpr int RNK = 64;

__device__ inline unsigned short f2bf(float f) {
    union { float f; unsigned u; } v; v.f = f;
    unsigned r = v.u + 0x7FFFu + ((v.u >> 16) & 1u);   // round-to-nearest-even
    return (unsigned short)(r >> 16);
}

// async global->LDS, 16 B per lane; LDS dest = wave-uniform base + lane*16
__device__ inline void gload_lds16(const float* g, char* lds_base) {
    __builtin_amdgcn_global_load_lds(
        (const __attribute__((address_space(1))) void*)g,
        (__attribute__((address_space(3))) void*)lds_base, 16, 0, 0);
}

// ---------------------------------------------------------------------------
// Fragment-major layout: block (tile,slice) holds the 64 lanes' bf16x8
// contiguously; every wave fragment load = one coalesced 1 KB instruction.
// ---------------------------------------------------------------------------
__global__ __launch_bounds__(256) void k_prep(const float* __restrict__ A,
                                              const float* __restrict__ B,
                                              unsigned short* __restrict__ Afrag,
                                              unsigned short* __restrict__ Atfrag,
                                              unsigned short* __restrict__ Bfrag) {
    int i = blockIdx.x * 256 + threadIdx.x;          // 0 .. 262143
    unsigned short ab = f2bf(A[i]);
    int n = i >> 12, k = i & 4095;                   // A[n][k]
    Afrag[(((k >> 5) << 2) + (n >> 4)) * 512 +
          ((((k >> 3) & 3) << 4) + (n & 15)) * 8 + (k & 7)] = ab;
    Atfrag[(((k >> 4) << 1) + (n >> 5)) * 512 +
           ((((n >> 3) & 3) << 4) + (k & 15)) * 8 + (n & 7)] = ab;
    unsigned short bb = f2bf(B[i]);
    int o = i >> 6, r = i & 63;
    Bfrag[(((o >> 4) << 1) + (r >> 5)) * 512 +
          ((((r >> 3) & 3) << 4) + (o & 15)) * 8 + (r & 7)] = bb;
}

// ---------------------------------------------------------------------------
// kAB: ONE dispatch, two roles; bodies are r11's k1_xa / k2_norm verbatim.
//   blocks    0..255  : k2_norm role (bw stream starts at t=0)
//   blocks 256..1279  : k1_xa role (x stream)
// Both streams (x 134 MB + bw 67 MB) now flow concurrently; 1280 blocks at
// ~4/CU residency leaves a queue that staggers block phases.
// ---------------------------------------------------------------------------
__global__ __launch_bounds__(256) void kAB(const float* __restrict__ x,
                                           const unsigned short* __restrict__ Afrag,
                                           float* __restrict__ pxa,
                                           const float* __restrict__ bw,
                                           const unsigned short* __restrict__ Bfrag,
                                           const unsigned short* __restrict__ Atfrag,
                                           float* __restrict__ pn) {
    __shared__ __align__(16) char smem[33024];
    char* buf0 = smem;
    char* buf1 = smem + 16384;
    int tid = threadIdx.x;
    int wid = tid >> 6, lane = tid & 63;
    int row = lane & 15, kq = lane >> 4;
    int lane8 = lane * 8;
    int swzr = (row & 7) << 4;

    if (blockIdx.x >= 256) {
        // ---------------- role 1: xa GEMM (r11 k1_xa) ----------------
        int bid = blockIdx.x - 256;
        float (*red)[1024] = (float (*)[1024])smem;  // aliases buf0 after loop
        int mt = bid & 511, kpart = bid >> 9;
        int m0 = mt * 16;
        const float* xbase = x + (size_t)m0 * DIN + kpart * 2048;

        f32x4 acc0 = {0.f, 0.f, 0.f, 0.f};
        f32x4 acc1 = acc0, acc2 = acc0, acc3 = acc0;
        bf16x8 setA[8], setB[8];

        auto STAGE = [&](char* buf, int c) {
            #pragma unroll
            for (int j = 0; j < 4; ++j) {
                int r = wid * 4 + j;
                int srcb = (lane * 16) ^ ((r & 7) << 4);
                const float* g = xbase + (size_t)r * DIN + c * 256 + (srcb >> 2);
                gload_lds16(g, buf + r * 1024);
            }
        };
        auto AFRAG = [&](bf16x8* set, int c) {
            #pragma unroll
            for (int s = 0; s < 2; ++s) {
                int ks = kpart * 64 + c * 8 + wid * 2 + s;
                const unsigned short* ap = Afrag + (size_t)ks * 2048 + lane8;
                set[s * 4 + 0] = *(const bf16x8*)(ap);
                set[s * 4 + 1] = *(const bf16x8*)(ap + 512);
                set[s * 4 + 2] = *(const bf16x8*)(ap + 1024);
                set[s * 4 + 3] = *(const bf16x8*)(ap + 1536);
            }
        };
        auto COMPUTE = [&](const char* buf, const bf16x8* set) {
            #pragma unroll
            for (int s = 0; s < 2; ++s) {
                int kbyte = wid * 256 + s * 128 + kq * 32;
                f32x4 xlo = *(const f32x4*)(buf + row * 1024 + ((kbyte) ^ swzr));
                f32x4 xhi = *(const f32x4*)(buf + row * 1024 + ((kbyte + 16) ^ swzr));
                bf16x8 af;
                #pragma unroll
                for (int j = 0; j < 4; ++j) {
                    af[j] = (__bf16)xlo[j];
                    af[j + 4] = (__bf16)xhi[j];
                }
                acc0 = MFMA16(af, set[s * 4 + 0], acc0);
                acc1 = MFMA16(af, set[s * 4 + 1], acc1);
                acc2 = MFMA16(af, set[s * 4 + 2], acc2);
                acc3 = MFMA16(af, set[s * 4 + 3], acc3);
            }
        };

        STAGE(buf0, 0); AFRAG(setA, 0);
        __syncthreads();
        #pragma unroll
        for (int c = 0; c < 8; c += 2) {
            if (c + 1 < 8) { STAGE(buf1, c + 1); AFRAG(setB, c + 1); }
            COMPUTE(buf0, setA);
            __syncthreads();
            if (c + 2 < 8) { STAGE(buf0, c + 2); AFRAG(setA, c + 2); }
            if (c + 1 < 8) COMPUTE(buf1, setB);
            __syncthreads();
        }

        int mb = kq * 4;                              // C: row=(lane>>4)*4+reg
        #pragma unroll
        for (int rg = 0; rg < 4; ++rg) {
            red[wid][(mb + rg) * 64 + row]      = acc0[rg];
            red[wid][(mb + rg) * 64 + 16 + row] = acc1[rg];
            red[wid][(mb + rg) * 64 + 32 + row] = acc2[rg];
            red[wid][(mb + rg) * 64 + 48 + row] = acc3[rg];
        }
        __syncthreads();
        #pragma unroll
        for (int e = tid; e < 1024; e += 256) {
            float s = red[0][e] + red[1][e] + red[2][e] + red[3][e];
            pxa[(size_t)kpart * M_TOT * RNK + (size_t)(m0 + (e >> 6)) * RNK + (e & 63)] = s;
        }
    } else {
        // ---------------- role 2: DoRA norm partials (r11 k2_norm) ----------
        int bid = blockIdx.x;
        float (*part)[16] = (float (*)[16])(smem + 32768);
        int ot = bid & 255, ipart = 0;
        // 256 blocks handle all 4 iparts? No: keep r11 grid shape 1024 ->
        // here 256 blocks each do ALL 4 iparts sequentially is too serial;
        // instead: 256 blocks, each covers one o-tile over the FULL 4096 i
        // as 16 chunks (same per-chunk template).
        int o0 = ot * 16;
        const float* bwbase = bw + (size_t)o0 * DIN;

        bf16x8 b0 = *(const bf16x8*)(Bfrag + (size_t)(ot * 2) * 512 + lane8);
        bf16x8 b1 = *(const bf16x8*)(Bfrag + (size_t)(ot * 2 + 1) * 512 + lane8);

        f32x4 nacc = {0.f, 0.f, 0.f, 0.f};
        bf16x8 setA[8], setB[8];

        auto STAGE = [&](char* buf, int c) {
            #pragma unroll
            for (int j = 0; j < 4; ++j) {
                int r = wid * 4 + j;
                int srcb = (lane * 16) ^ ((r & 7) << 4);
                const float* g = bwbase + (size_t)r * DIN + c * 256 + (srcb >> 2);
                gload_lds16(g, buf + r * 1024);
            }
        };
        auto ATFRAG = [&](bf16x8* set, int c) {
            #pragma unroll
            for (int g = 0; g < 4; ++g) {
                int it = c * 16 + wid * 4 + g;
                const unsigned short* atp = Atfrag + (size_t)it * 1024 + lane8;
                set[g * 2]     = *(const bf16x8*)(atp);
                set[g * 2 + 1] = *(const bf16x8*)(atp + 512);
            }
        };
        auto COMPUTE = [&](const char* buf, const bf16x8* set) {
            #pragma unroll
            for (int g = 0; g < 4; ++g) {
                f32x4 d = {0.f, 0.f, 0.f, 0.f};
                d = MFMA16(set[g * 2], b0, d);       // delta[o=o0+row][i=..+kq*4+rg]
                d = MFMA16(set[g * 2 + 1], b1, d);
                int ibyte = wid * 256 + g * 64 + kq * 16;
                f32x4 wv = *(const f32x4*)(buf + row * 1024 + (ibyte ^ swzr));
                #pragma unroll
                for (int rg = 0; rg < 4; ++rg) {
                    float w = wv[rg] + 2.0f * d[rg];
                    nacc[rg] += w * w;
                }
            }
        };

        STAGE(buf0, 0); ATFRAG(setA, 0);
        __syncthreads();
        #pragma unroll 2
        for (int c = 0; c < 16; c += 2) {
            if (c + 1 < 16) { STAGE(buf1, c + 1); ATFRAG(setB, c + 1); }
            COMPUTE(buf0, setA);
            __syncthreads();
            if (c + 2 < 16) { STAGE(buf0, c + 2); ATFRAG(setA, c + 2); }
            if (c + 1 < 16) COMPUTE(buf1, setB);
            __syncthreads();
        }

        float ns = nacc[0] + nacc[1] + nacc[2] + nacc[3];
        ns += __shfl_xor(ns, 16, 64);
        ns += __shfl_xor(ns, 32, 64);
        if (kq == 0) part[wid][row] = ns;
        __syncthreads();
        if (tid < 16)
            pn[o0 + tid] = part[0][tid] + part[1][tid] + part[2][tid] + part[3][tid];
    }
}

// ---------------------------------------------------------------------------
// kfin: ONE dispatch, two roles.
//   blocks 0..511 : xa frag-major bf16 <- sum of 2 f32 partials (k1_fin)
//   blocks 512..527: mscale[o] = mag[o] / (sqrt(pn[o]) + eps)
// ---------------------------------------------------------------------------
__global__ __launch_bounds__(256) void kfin(const float* __restrict__ pxa,
                                            unsigned short* __restrict__ xafrag,
                                            const float* __restrict__ pn,
                                            const float* __restrict__ mag,
                                            float* __restrict__ mscale) {
    int tid = threadIdx.x;
    if (blockIdx.x < 512) {
        int mt = blockIdx.x;
        int e0 = tid * 4;
        size_t o = (size_t)(mt * 16 + (e0 >> 6)) * RNK + (e0 & 63);
        f32x4 s0 = *(const f32x4*)(pxa + o);
        f32x4 s1 = *(const f32x4*)(pxa + (size_t)M_TOT * RNK + o);
        int ml = e0 >> 6, r0 = e0 & 63;
        ushort4 h;
        h.x = f2bf(s0[0] + s1[0]);
        h.y = f2bf(s0[1] + s1[1]);
        h.z = f2bf(s0[2] + s1[2]);
        h.w = f2bf(s0[3] + s1[3]);
        *(ushort4*)&xafrag[((size_t)(mt * 2 + (r0 >> 5))) * 512 +
                           ((((r0 >> 3) & 3) << 4) + ml) * 8 + (r0 & 7)] = h;
    } else {
        int o = (int)(blockIdx.x - 512) * 256 + tid;
        mscale[o] = mag[o] / (sqrtf(pn[o]) + 1e-8f);
    }
}

// ---------------------------------------------------------------------------
// kB: out = (base_output + 2 * xa @ lora_B^T) * mscale   (proven r7/r9 form)
// ---------------------------------------------------------------------------
__global__ __launch_bounds__(256) void kB(const float* __restrict__ base,
                                          const unsigned short* __restrict__ xafrag,
                                          const unsigned short* __restrict__ Bfrag,
                                          const float* __restrict__ mscale,
                                          float* __restrict__ out) {
    __shared__ float dls[32][260];                   // 33.3 KB, +4 pad
    int tid = threadIdx.x;
    int wid = tid >> 6, lane = tid & 63;
    int row = lane & 15, kq = lane >> 4;
    int m0 = blockIdx.x * 32;
    int n0 = blockIdx.y * 256;
    int col = n0 + lane * 4;
    int lane8 = lane * 8;

    f32x4 bpre[2][4];
    #pragma unroll
    for (int h = 0; h < 2; ++h)
        #pragma unroll
        for (int r = 0; r < 4; ++r)
            bpre[h][r] = __builtin_nontemporal_load(
                (const f32x4*)(base + (size_t)(m0 + h * 16 + wid * 4 + r) * DOUT + col));
    f32x4 msv = *(const f32x4*)(mscale + col);

    bf16x8 xb0[2], xb1[2];
    #pragma unroll
    for (int h = 0; h < 2; ++h) {
        size_t mt = (size_t)(blockIdx.x * 2 + h);
        xb0[h] = *(const bf16x8*)(xafrag + (mt * 2) * 512 + lane8);
        xb1[h] = *(const bf16x8*)(xafrag + (mt * 2 + 1) * 512 + lane8);
    }

    #pragma unroll
    for (int nt = 0; nt < 4; ++nt) {
        size_t ntg = (size_t)((n0 + wid * 64 + nt * 16) >> 4);
        bf16x8 a0 = *(const bf16x8*)(Bfrag + (ntg * 2) * 512 + lane8);
        bf16x8 a1 = *(const bf16x8*)(Bfrag + (ntg * 2 + 1) * 512 + lane8);
        #pragma unroll
        for (int h = 0; h < 2; ++h) {
            f32x4 acc = {0.f, 0.f, 0.f, 0.f};
            acc = MFMA16(a0, xb0[h], acc);           // lane: delta[m=row][nloc=kq*4+rg]
            acc = MFMA16(a1, xb1[h], acc);
            *(f32x4*)&dls[h * 16 + row][wid * 64 + nt * 16 + kq * 4] = acc;
        }
    }
    __syncthreads();

    #pragma unroll
    for (int h = 0; h < 2; ++h)
        #pragma unroll
        for (int r = 0; r < 4; ++r) {
            int m = h * 16 + wid * 4 + r;
            f32x4 d = *(const f32x4*)&dls[m][lane * 4];
            size_t gidx = (size_t)(m0 + m) * DOUT + col;
            f32x4 o;
            #pragma unroll
            for (int j = 0; j < 4; ++j) o[j] = (bpre[h][r][j] + 2.0f * d[j]) * msv[j];
            __builtin_nontemporal_store(o, (f32x4*)(out + gidx));
        }
}

extern "C" void kernel_launch(void* const* d_in, const int* in_sizes, int n_in,
                              void* d_out, int out_size, void* d_ws, size_t ws_size,
                              hipStream_t stream) {
    const float* x    = (const float*)d_in[0];   // [2,4096,4096]
    const float* base = (const float*)d_in[1];   // [2,4096,4096]
    const float* bw   = (const float*)d_in[2];   // [4096,4096]
    const float* lA   = (const float*)d_in[3];   // [64,4096]
    const float* lB   = (const float*)d_in[4];   // [4096,64]
    const float* mag  = (const float*)d_in[5];   // [4096]
    float* out = (float*)d_out;

    char* ws = (char*)d_ws;
    unsigned short* Afrag  = (unsigned short*)(ws);                  // 512 KB
    unsigned short* Atfrag = (unsigned short*)(ws + (512u << 10));   // 512 KB
    unsigned short* Bfrag  = (unsigned short*)(ws + (1024u << 10));  // 512 KB
    unsigned short* xafrag = (unsigned short*)(ws + (1536u << 10));  // 1 MB
    float*          pxa    = (float*)(ws + (2560u << 10));           // 4 MB
    float*          pn     = (float*)(ws + (6656u << 10));           // 16 KB
    float*          msc    = (float*)(ws + (6720u << 10));           // 16 KB

    hipLaunchKernelGGL(k_prep, dim3(1024), dim3(256), 0, stream, lA, lB, Afrag, Atfrag, Bfrag);
    hipLaunchKernelGGL(kAB, dim3(1280), dim3(256), 0, stream,
                       x, Afrag, pxa, bw, Bfrag, Atfrag, pn);
    hipLaunchKernelGGL(kfin, dim3(528), dim3(256), 0, stream, pxa, xafrag, pn, mag, msc);
    hipLaunchKernelGGL(kB, dim3(M_TOT / 32, DOUT / 256), dim3(256), 0, stream,
                       base, xafrag, Bfrag, msc, out);
}